// Round 6
// baseline (362.229 us; speedup 1.0000x reference)
//
#include <hip/hip_runtime.h>

// ---------------------------------------------------------------------------
// GraphTransformerWithPooling on MI355X (gfx950)
// R18b: R18 with the nontemporal-store compile fix (pack uint2 -> u64; the
// builtin rejects HIP_vector_type). Structural split, unchanged rationale:
// R14 (2x waves -> slower), R16 (working-set halving -> null), R17
// (bytes+lines halved -> only -10%) triangulate the gather to per-CU
// random-MISS service throughput (MSHR-bound ~3.6 TB/s). Fix: make the
// random reads L2-HITS. Since S is linear, each pool layer is S(M W) + d b:
// (1) gemm_pass streams M, computes Y = M W, writes Y in 8 contiguous
// column SLABS (slab = N x 16 bf16 = 1.6 MB); (2) gather_pass grid
// (tile, s), s = blockIdx.x & 7 -> round-robin pins slab s to XCD s, slab
// resident in that XCD's 4 MiB L2 (plus linear warm) -> random reads hit
// L2, no MSHR pressure. All-bf16 numerics restored (fp8 dropped).
// 13 dispatches: prep, hist, scan_fuse, fill, (gemm+gather) x4, gemm_out.
// ---------------------------------------------------------------------------

static inline int ceil_div(int a, int b) { return (a + b - 1) / b; }

typedef __attribute__((ext_vector_type(8))) short bf16x8;  // MFMA A/B frag
typedef __attribute__((ext_vector_type(4))) float f32x4;   // MFMA C/D frag

__device__ inline unsigned short f2bf(float f) {   // fp32 -> bf16 RNE
    unsigned u = __float_as_uint(f);
    return (unsigned short)((u + 0x7fffu + ((u >> 16) & 1u)) >> 16);
}

// ---------------- prep: zero cursor/stat, cast x->bf16, W frags -------------
// Frag layout t = ((ct*4+c)*64+lane)*8+j <-> k = c*32+(lane>>4)*8+j,
//   col = ct*16+(lane&15); a wave's 16B load of hi[] is the MFMA B fragment.

__device__ void wprep_dev(const float* __restrict__ W, unsigned short* __restrict__ hi,
                          int total, int C, int g0, int G) {
    for (int t = g0; t < total; t += G) {
        int j = t & 7;
        int lane = (t >> 3) & 63;
        int f = t >> 9;
        int c = f & 3, ct = f >> 2;
        int k = c * 32 + (lane >> 4) * 8 + j;
        int col = ct * 16 + (lane & 15);
        hi[t] = f2bf(W[(size_t)k * C + col]);
    }
}

__global__ __launch_bounds__(256) void prep_kernel(const float* __restrict__ x,
                                                   const float* __restrict__ W1,
                                                   const float* __restrict__ W2,
                                                   const float* __restrict__ Wout,
                                                   unsigned short* __restrict__ xb,
                                                   unsigned short* __restrict__ W1hi,
                                                   unsigned short* __restrict__ W2hi,
                                                   unsigned short* __restrict__ Wohi,
                                                   int* __restrict__ cursor,
                                                   unsigned* __restrict__ stat,
                                                   int N, int nChunks) {
    int g0 = blockIdx.x * 256 + threadIdx.x;
    int G = gridDim.x * 256;
    for (int i = g0; i < N; i += G) cursor[i] = 0;
    for (int i = g0; i < nChunks; i += G) stat[i] = 0;

    int nq = N * 32;   // float4 count of x
    for (int i = g0; i < nq; i += G) {
        float4 v = ((const float4*)x)[i];
        ushort4 o;
        o.x = f2bf(v.x); o.y = f2bf(v.y); o.z = f2bf(v.z); o.w = f2bf(v.w);
        ((ushort4*)xb)[i] = o;
    }

    wprep_dev(W1, W1hi, 128 * 128, 128, g0, G);
    wprep_dev(W2, W2hi, 128 * 128, 128, g0, G);
    wprep_dev(Wout, Wohi, 128 * 64, 64, g0, G);
}

// ---------------- CSR build ----------------

__global__ __launch_bounds__(256) void hist_kernel(const int* __restrict__ dst,
                                                   int* __restrict__ deg, int E) {
    int e = blockIdx.x * 256 + threadIdx.x;
    if (e < E) atomicAdd(&deg[dst[e]], 1);
}

// Merged scan: publish chunk total (flag bit), spin-read predecessors
// (publishers never wait -> no deadlock). Writes rp, seeds fill cursor.
__global__ __launch_bounds__(256) void scan_fuse_kernel(const int* __restrict__ deg,
                                                        int* __restrict__ rp,
                                                        int* __restrict__ cursor,
                                                        unsigned* __restrict__ stat,
                                                        int N) {
    __shared__ int s[256];
    int c = blockIdx.x, tid = threadIdx.x;
    int i = c * 256 + tid;
    int v = (i < N) ? deg[i] : 0;
    s[tid] = v;
    __syncthreads();
    for (int off = 1; off < 256; off <<= 1) {
        int t = (tid >= off) ? s[tid - off] : 0;
        __syncthreads();
        s[tid] += t;
        __syncthreads();
    }
    int loc = s[tid] - v;
    int tot = s[255];
    __syncthreads();
    if (tid == 0) atomicExch(&stat[c], (unsigned)tot | 0x80000000u);

    unsigned mine = 0;
    if (tid < c) {
        unsigned u;
        do { u = atomicAdd(&stat[tid], 0u); } while (!(u & 0x80000000u));
        mine = u & 0x7fffffffu;
    }
    s[tid] = (int)mine;
    __syncthreads();
    for (int off = 128; off >= 1; off >>= 1) {
        if (tid < off) s[tid] += s[tid + off];
        __syncthreads();
    }
    int prefix = s[0];
    if (i <= N) {
        int val = loc + prefix;
        rp[i] = val;
        if (i < N) cursor[i] = val;
    }
}

__global__ __launch_bounds__(256) void fill_kernel(const int* __restrict__ src,
                                                   const int* __restrict__ dst,
                                                   int* __restrict__ cursor,
                                                   unsigned short* __restrict__ es, int E) {
    int e = blockIdx.x * 256 + threadIdx.x;
    if (e < E) {
        int p = atomicAdd(&cursor[dst[e]], 1);
        es[p] = (unsigned short)src[e];
    }
}

// ---------------- gemm_pass: Y = A(row-major bf16) @ W -> slabbed bf16 ------
// Block = 64 rows; 4 waves; A-frags read directly from global (streamed,
// every byte once); W frags L2-hot. Output slab s holds cols [s*16,s*16+16)
// contiguously: Ys[s*N*16 + row*16 + c]. C/D: col = lane&15, row = lq*4+reg.

__global__ __launch_bounds__(256) void gemm_pass(const unsigned short* __restrict__ A,
                                                 const uint4* __restrict__ Whi,
                                                 unsigned short* __restrict__ Ys,
                                                 int n, int N) {
    int tid = threadIdx.x;
    int r0 = blockIdx.x * 64;
    int wave = tid >> 6, lane = tid & 63;
    int lm = lane & 15, lq = lane >> 4;

    f32x4 acc[4][2];
#pragma unroll
    for (int rt = 0; rt < 4; ++rt)
#pragma unroll
        for (int t = 0; t < 2; ++t)
            acc[rt][t] = (f32x4){0.f, 0.f, 0.f, 0.f};

#pragma unroll
    for (int c = 0; c < 4; ++c) {
        bf16x8 afr[4];
#pragma unroll
        for (int rt = 0; rt < 4; ++rt)
            afr[rt] = *(const bf16x8*)(A + (size_t)(r0 + rt * 16 + lm) * 128 + c * 32 + lq * 8);
#pragma unroll
        for (int t = 0; t < 2; ++t) {
            uint4 uh = Whi[((wave * 2 + t) * 4 + c) * 64 + lane];
            bf16x8 wh = *(const bf16x8*)&uh;
#pragma unroll
            for (int rt = 0; rt < 4; ++rt)
                acc[rt][t] = __builtin_amdgcn_mfma_f32_16x16x32_bf16(afr[rt], wh, acc[rt][t], 0, 0, 0);
        }
    }

#pragma unroll
    for (int t = 0; t < 2; ++t) {
        int s = wave * 2 + t;
#pragma unroll
        for (int rt = 0; rt < 4; ++rt) {
#pragma unroll
            for (int r = 0; r < 4; ++r) {
                int row = r0 + rt * 16 + lq * 4 + r;
                if (row < n)
                    Ys[(size_t)s * N * 16 + (size_t)row * 16 + lm] = f2bf(acc[rt][t][r]);
            }
        }
    }
}

// ---------------- gather_pass: M_next[:,slice s] = S(Y_s) + d*b_s -----------
// Grid = tiles*8; s = bid & 7 -> round-robin pins slab s to XCD s; slab
// (N x 16 bf16 = 1.6 MB) is L2-resident there. Early blocks linearly warm
// the slab. 64 groups of 4 lanes = 64 nodes; group gid handles degree-rank
// gid (waves internally balanced). Edge indices LDS-staged. fp32 acc,
// nontemporal row-major bf16 output (don't pollute the slab-holding L2).

__device__ inline void acc_row4(float* a, uint2 v) {
    a[0] += __uint_as_float(v.x << 16);
    a[1] += __uint_as_float(v.x & 0xffff0000u);
    a[2] += __uint_as_float(v.y << 16);
    a[3] += __uint_as_float(v.y & 0xffff0000u);
}

template <bool RELU>
__global__ __launch_bounds__(256) void gather_pass(const unsigned short* __restrict__ Ys,
                                                   const int* __restrict__ rp,
                                                   const unsigned short* __restrict__ es,
                                                   const float* __restrict__ bvec,
                                                   unsigned short* __restrict__ Mout,
                                                   int n, int N) {
    constexpr int ECAP = 1280;
    __shared__ unsigned short esl[ECAP];
    __shared__ int rpl[65];
    __shared__ unsigned char perm[64];

    int tid = threadIdx.x;
    int s = blockIdx.x & 7;
    int t = blockIdx.x >> 3;
    int r0 = t * 64;

    const unsigned short* slab = Ys + (size_t)s * N * 16;

    // linear warm: first ~N*16/(256*8) blocks per slab stream it into L2
    {
        int widx = t * 256 + tid;                 // uint4 index (8 ushorts)
        if (widx * 8 < N * 16) {
            uint4 w = ((const uint4*)slab)[widx];
            asm volatile("" :: "v"(w.x), "v"(w.y), "v"(w.z), "v"(w.w));
        }
    }

    if (tid < 65) {
        int gi = r0 + tid;
        if (gi > n) gi = n;
        rpl[tid] = rp[gi];
    }
    __syncthreads();

    int ebase = rpl[0];
    int ecnt = rpl[64] - ebase;
    if (ecnt > ECAP) ecnt = ECAP;

    // rank by degree (desc; ties by index); other threads stage edge indices
    if (tid < 64) {
        int di = rpl[tid + 1] - rpl[tid];
        int rank = 0;
        for (int j = 0; j < 64; ++j) {
            int dj = rpl[j + 1] - rpl[j];
            rank += (dj > di) || (dj == di && j < tid);
        }
        perm[rank] = (unsigned char)tid;
    }
    for (int i = tid; i < ecnt; i += 256) esl[i] = es[ebase + i];
    __syncthreads();

    int gid = tid >> 2, ln = tid & 3;
    int nl = perm[gid];
    int beg = rpl[nl], end = rpl[nl + 1];
    int pbeg = beg - ebase, pend = end - ebase;
    int pm = pend < ecnt ? pend : ecnt;
    const unsigned short* base = slab + ln * 4;

    float a[4] = {};
    int p = pbeg;
    for (; p + 8 <= pm; p += 8) {
        int s0 = esl[p],     s1 = esl[p + 1], s2 = esl[p + 2], s3 = esl[p + 3];
        int s4 = esl[p + 4], s5 = esl[p + 5], s6 = esl[p + 6], s7 = esl[p + 7];
        uint2 v0 = *(const uint2*)(base + (size_t)s0 * 16);
        uint2 v1 = *(const uint2*)(base + (size_t)s1 * 16);
        uint2 v2 = *(const uint2*)(base + (size_t)s2 * 16);
        uint2 v3 = *(const uint2*)(base + (size_t)s3 * 16);
        uint2 v4 = *(const uint2*)(base + (size_t)s4 * 16);
        uint2 v5 = *(const uint2*)(base + (size_t)s5 * 16);
        uint2 v6 = *(const uint2*)(base + (size_t)s6 * 16);
        uint2 v7 = *(const uint2*)(base + (size_t)s7 * 16);
        acc_row4(a, v0); acc_row4(a, v1); acc_row4(a, v2); acc_row4(a, v3);
        acc_row4(a, v4); acc_row4(a, v5); acc_row4(a, v6); acc_row4(a, v7);
    }
    for (; p + 4 <= pm; p += 4) {
        int s0 = esl[p], s1 = esl[p + 1], s2 = esl[p + 2], s3 = esl[p + 3];
        uint2 v0 = *(const uint2*)(base + (size_t)s0 * 16);
        uint2 v1 = *(const uint2*)(base + (size_t)s1 * 16);
        uint2 v2 = *(const uint2*)(base + (size_t)s2 * 16);
        uint2 v3 = *(const uint2*)(base + (size_t)s3 * 16);
        acc_row4(a, v0); acc_row4(a, v1); acc_row4(a, v2); acc_row4(a, v3);
    }
    for (; p < pm; ++p) {
        uint2 v = *(const uint2*)(base + (size_t)esl[p] * 16);
        acc_row4(a, v);
    }
    for (; p < pend; ++p) {   // overflow fallback (ecnt == total in practice)
        uint2 v = *(const uint2*)(base + (size_t)es[ebase + p] * 16);
        acc_row4(a, v);
    }

    int node = r0 + nl;
    if (node < n) {
        float deg = (float)(end - beg);
        float4 bv = *(const float4*)(bvec + s * 16 + ln * 4);
        float v0 = a[0] + deg * bv.x;
        float v1 = a[1] + deg * bv.y;
        float v2 = a[2] + deg * bv.z;
        float v3 = a[3] + deg * bv.w;
        if (RELU) {
            v0 = fmaxf(v0, 0.f); v1 = fmaxf(v1, 0.f);
            v2 = fmaxf(v2, 0.f); v3 = fmaxf(v3, 0.f);
        }
        unsigned lo = (unsigned)f2bf(v0) | ((unsigned)f2bf(v1) << 16);
        unsigned hi = (unsigned)f2bf(v2) | ((unsigned)f2bf(v3) << 16);
        unsigned long long o = (unsigned long long)lo | ((unsigned long long)hi << 32);
        __builtin_nontemporal_store(
            o, (unsigned long long*)(Mout + (size_t)node * 128 + s * 16 + ln * 4));
    }
}

// ---------------- gemm_out: out = Z @ Wout + bout (fp32) --------------------

__global__ __launch_bounds__(256) void gemm_out(const unsigned short* __restrict__ A,
                                                const uint4* __restrict__ Wof,
                                                const float* __restrict__ bout,
                                                float* __restrict__ out, int n) {
    int tid = threadIdx.x;
    int r0 = blockIdx.x * 64;
    int wave = tid >> 6, lane = tid & 63;
    int lm = lane & 15, lq = lane >> 4;

    f32x4 acc[4];
#pragma unroll
    for (int rt = 0; rt < 4; ++rt) acc[rt] = (f32x4){0.f, 0.f, 0.f, 0.f};

#pragma unroll
    for (int c = 0; c < 4; ++c) {
        bf16x8 afr[4];
#pragma unroll
        for (int rt = 0; rt < 4; ++rt)
            afr[rt] = *(const bf16x8*)(A + (size_t)(r0 + rt * 16 + lm) * 128 + c * 32 + lq * 8);
        uint4 uw = Wof[(wave * 4 + c) * 64 + lane];
        bf16x8 wf = *(const bf16x8*)&uw;
#pragma unroll
        for (int rt = 0; rt < 4; ++rt)
            acc[rt] = __builtin_amdgcn_mfma_f32_16x16x32_bf16(afr[rt], wf, acc[rt], 0, 0, 0);
    }

    int col = wave * 16 + lm;
    float bo = bout[col];
#pragma unroll
    for (int rt = 0; rt < 4; ++rt) {
#pragma unroll
        for (int r = 0; r < 4; ++r) {
            int row = r0 + rt * 16 + lq * 4 + r;
            if (row < n)
                out[(size_t)row * 64 + col] = acc[rt][r] + bo;
        }
    }
}

// ---------------- Launch ----------------

extern "C" void kernel_launch(void* const* d_in, const int* in_sizes, int n_in,
                              void* d_out, int out_size, void* d_ws, size_t ws_size,
                              hipStream_t stream) {
    const float* x    = (const float*)d_in[0];
    const int*   ei   = (const int*)d_in[1];
    const float* W1   = (const float*)d_in[2];
    const float* b1   = (const float*)d_in[3];
    const float* W2   = (const float*)d_in[4];
    const float* b2   = (const float*)d_in[5];
    const float* Wout = (const float*)d_in[6];
    const float* bout = (const float*)d_in[7];
    float*       out  = (float*)d_out;

    const int N = in_sizes[0] / 128;
    const int E = in_sizes[1] / 2;
    const int* src = ei;
    const int* dst = ei + E;

    char* ws = (char*)d_ws;
    auto take = [&](size_t bytes) {
        char* p = ws;
        ws += (bytes + 255) & ~(size_t)255;
        return p;
    };
    unsigned short* BM = (unsigned short*)take((size_t)N * 128 * 2);  // xb, later Z
    unsigned short* mA = (unsigned short*)take((size_t)N * 128 * 2);
    unsigned short* Ys = (unsigned short*)take((size_t)N * 128 * 2);  // 8 slabs
    unsigned short* W1hi = (unsigned short*)take(128 * 128 * 2);
    unsigned short* W2hi = (unsigned short*)take(128 * 128 * 2);
    unsigned short* Wohi = (unsigned short*)take(128 * 64 * 2);
    int* rp      = (int*)take((size_t)(N + 1) * sizeof(int));
    int* cursor  = (int*)take((size_t)N * sizeof(int));
    unsigned short* es = (unsigned short*)take((size_t)E * sizeof(unsigned short));
    unsigned* stat = (unsigned*)take(4096);

    const int nChunks = ceil_div(N + 1, 256);   // 196 for N=50000 (<=256 required)
    const int tiles64 = ceil_div(N, 64);

    prep_kernel<<<256, 256, 0, stream>>>(x, W1, W2, Wout, BM, W1hi, W2hi, Wohi,
                                         cursor, stat, N, nChunks);
    hist_kernel<<<ceil_div(E, 256), 256, 0, stream>>>(dst, cursor, E);
    scan_fuse_kernel<<<nChunks, 256, 0, stream>>>(cursor, rp, cursor, stat, N);
    fill_kernel<<<ceil_div(E, 256), 256, 0, stream>>>(src, dst, cursor, es, E);

    // L1: x1 = S(x W1) + d b1
    gemm_pass<<<tiles64, 256, 0, stream>>>(BM, (const uint4*)W1hi, Ys, N, N);
    gather_pass<false><<<tiles64 * 8, 256, 0, stream>>>(Ys, rp, es, b1, mA, N, N);
    // L2: h = relu(S(x1 W1) + d b1)
    gemm_pass<<<tiles64, 256, 0, stream>>>(mA, (const uint4*)W1hi, Ys, N, N);
    gather_pass<true><<<tiles64 * 8, 256, 0, stream>>>(Ys, rp, es, b1, BM, N, N);
    // L3: h1 = S(h W2) + d b2
    gemm_pass<<<tiles64, 256, 0, stream>>>(BM, (const uint4*)W2hi, Ys, N, N);
    gather_pass<false><<<tiles64 * 8, 256, 0, stream>>>(Ys, rp, es, b2, mA, N, N);
    // L4: z = relu(S(h1 W2) + d b2)
    gemm_pass<<<tiles64, 256, 0, stream>>>(mA, (const uint4*)W2hi, Ys, N, N);
    gather_pass<true><<<tiles64 * 8, 256, 0, stream>>>(Ys, rp, es, b2, BM, N, N);
    // out = z Wout + bout
    gemm_out<<<tiles64, 256, 0, stream>>>(BM, (const uint4*)Wohi, bout, out, N);
}

// Round 7
// 297.242 us; speedup vs baseline: 1.2186x; 1.2186x over previous
//
#include <hip/hip_runtime.h>

// ---------------------------------------------------------------------------
// GraphTransformerWithPooling on MI355X (gfx950)
// R19: 2-slab L2-resident gather + reassociated streaming GEMM.
// Model from R15/R17/R18b: gather ~= nblocks*fixed + requests*(3cy L2-hit |
// 30cy LLC-miss). R18b's 8-slab paid 8x fixed + 8x requests; optimum is 2
// slabs: fp8 M half-row slab = N*64B = 3.2MB < 4MiB per-XCD L2 (resident).
// Grid tiles*2, s=bid&1 -> round-robin block->XCD puts slab parity on XCD
// parity; every XCD reads ONLY its resident slab -> all gather requests are
// L2 hits. One quantization/layer kept via (S M) W = S(M W): gather_pass
// computes H=S(M) bf16 (nontemporal out), gemm_pass streams H, applies
// W + deg*b (+ReLU; last layer chains Wout -> fp32 out), writes fp8 slabbed
// M_next. 12 dispatches: prep, hist, scan_fuse, fill, (gather+gemm) x4.
// ---------------------------------------------------------------------------

static inline int ceil_div(int a, int b) { return (a + b - 1) / b; }

typedef __attribute__((ext_vector_type(8))) short bf16x8;  // MFMA A/B frag
typedef __attribute__((ext_vector_type(4))) float f32x4;   // MFMA C/D frag
typedef __attribute__((ext_vector_type(2))) float f32x2;

__device__ inline unsigned short f2bf(float f) {   // fp32 -> bf16 RNE
    unsigned u = __float_as_uint(f);
    return (unsigned short)((u + 0x7fffu + ((u >> 16) & 1u)) >> 16);
}

__device__ inline unsigned char f2fp8(float f) {   // fp32 -> e4m3 RNE (sat)
    return (unsigned char)(__builtin_amdgcn_cvt_pk_fp8_f32(f, 0.f, 0u, false) & 0xffu);
}

// ---------------- prep: zero cursor/stat, cast x->fp8 SLABBED, W frags ------
// Slab layout: M[s*N*64 + row*64 + c64], s = col>>6, c64 = col&63 (bytes).
// W frag layout t = ((ct*4+c)*64+lane)*8+j <-> k = c*32+(lane>>4)*8+j,
//   col = ct*16+(lane&15); a wave's 16B load of hi[] is the MFMA B fragment.

__device__ void wprep_dev(const float* __restrict__ W, unsigned short* __restrict__ hi,
                          int total, int C, int g0, int G) {
    for (int t = g0; t < total; t += G) {
        int j = t & 7;
        int lane = (t >> 3) & 63;
        int f = t >> 9;
        int c = f & 3, ct = f >> 2;
        int k = c * 32 + (lane >> 4) * 8 + j;
        int col = ct * 16 + (lane & 15);
        hi[t] = f2bf(W[(size_t)k * C + col]);
    }
}

__global__ __launch_bounds__(256) void prep_kernel(const float* __restrict__ x,
                                                   const float* __restrict__ W1,
                                                   const float* __restrict__ W2,
                                                   const float* __restrict__ Wout,
                                                   unsigned* __restrict__ xb,   // slabbed fp8, u32 view
                                                   unsigned short* __restrict__ W1hi,
                                                   unsigned short* __restrict__ W2hi,
                                                   unsigned short* __restrict__ Wohi,
                                                   int* __restrict__ cursor,
                                                   unsigned* __restrict__ stat,
                                                   int N, int nChunks) {
    int g0 = blockIdx.x * 256 + threadIdx.x;
    int G = gridDim.x * 256;
    for (int i = g0; i < N; i += G) cursor[i] = 0;
    for (int i = g0; i < nChunks; i += G) stat[i] = 0;

    int nq = N * 32;   // float4 count of x; i = row*32 + j, cols [4j,4j+4)
    for (int i = g0; i < nq; i += G) {
        float4 v = ((const float4*)x)[i];
        unsigned w = __builtin_amdgcn_cvt_pk_fp8_f32(v.x, v.y, 0u, false);
        w = __builtin_amdgcn_cvt_pk_fp8_f32(v.z, v.w, w, true);
        int row = i >> 5, j = i & 31;
        int s = j >> 4;                       // slab
        xb[(size_t)s * N * 16 + (size_t)row * 16 + (j & 15)] = w;
    }

    wprep_dev(W1, W1hi, 128 * 128, 128, g0, G);
    wprep_dev(W2, W2hi, 128 * 128, 128, g0, G);
    wprep_dev(Wout, Wohi, 128 * 64, 64, g0, G);
}

// ---------------- CSR build ----------------

__global__ __launch_bounds__(256) void hist_kernel(const int* __restrict__ dst,
                                                   int* __restrict__ deg, int E) {
    int e = blockIdx.x * 256 + threadIdx.x;
    if (e < E) atomicAdd(&deg[dst[e]], 1);
}

__global__ __launch_bounds__(256) void scan_fuse_kernel(const int* __restrict__ deg,
                                                        int* __restrict__ rp,
                                                        int* __restrict__ cursor,
                                                        unsigned* __restrict__ stat,
                                                        int N) {
    __shared__ int s[256];
    int c = blockIdx.x, tid = threadIdx.x;
    int i = c * 256 + tid;
    int v = (i < N) ? deg[i] : 0;
    s[tid] = v;
    __syncthreads();
    for (int off = 1; off < 256; off <<= 1) {
        int t = (tid >= off) ? s[tid - off] : 0;
        __syncthreads();
        s[tid] += t;
        __syncthreads();
    }
    int loc = s[tid] - v;
    int tot = s[255];
    __syncthreads();
    if (tid == 0) atomicExch(&stat[c], (unsigned)tot | 0x80000000u);

    unsigned mine = 0;
    if (tid < c) {
        unsigned u;
        do { u = atomicAdd(&stat[tid], 0u); } while (!(u & 0x80000000u));
        mine = u & 0x7fffffffu;
    }
    s[tid] = (int)mine;
    __syncthreads();
    for (int off = 128; off >= 1; off >>= 1) {
        if (tid < off) s[tid] += s[tid + off];
        __syncthreads();
    }
    int prefix = s[0];
    if (i <= N) {
        int val = loc + prefix;
        rp[i] = val;
        if (i < N) cursor[i] = val;
    }
}

__global__ __launch_bounds__(256) void fill_kernel(const int* __restrict__ src,
                                                   const int* __restrict__ dst,
                                                   int* __restrict__ cursor,
                                                   unsigned short* __restrict__ es, int E) {
    int e = blockIdx.x * 256 + threadIdx.x;
    if (e < E) {
        int p = atomicAdd(&cursor[dst[e]], 1);
        es[p] = (unsigned short)src[e];
    }
}

// ---------------- gather_pass: H[:, 64*s:64*s+64] = S(M_s) ------------------
// Grid tiles*2, s = bid&1 (matches XCD parity under round-robin dispatch).
// Slab s (N*64B fp8 = 3.2MB) is L2-resident on its 4 XCDs; each same-XCD
// block warms one consecutive 16KB chunk (t>>2). 64 groups of 4 lanes;
// group g handles degree-rank g (waves get adjacent ranks). Edge indices
// LDS-staged. fp32 acc via v_cvt_pk_f32_fp8; bf16 nontemporal H out.

__device__ inline void acc16f(float* a, uint4 v) {
    f32x2 p;
    p = __builtin_amdgcn_cvt_pk_f32_fp8(v.x, false); a[0] += p[0];  a[1] += p[1];
    p = __builtin_amdgcn_cvt_pk_f32_fp8(v.x, true);  a[2] += p[0];  a[3] += p[1];
    p = __builtin_amdgcn_cvt_pk_f32_fp8(v.y, false); a[4] += p[0];  a[5] += p[1];
    p = __builtin_amdgcn_cvt_pk_f32_fp8(v.y, true);  a[6] += p[0];  a[7] += p[1];
    p = __builtin_amdgcn_cvt_pk_f32_fp8(v.z, false); a[8] += p[0];  a[9] += p[1];
    p = __builtin_amdgcn_cvt_pk_f32_fp8(v.z, true);  a[10] += p[0]; a[11] += p[1];
    p = __builtin_amdgcn_cvt_pk_f32_fp8(v.w, false); a[12] += p[0]; a[13] += p[1];
    p = __builtin_amdgcn_cvt_pk_f32_fp8(v.w, true);  a[14] += p[0]; a[15] += p[1];
}

__global__ __launch_bounds__(256) void gather_pass(const unsigned char* __restrict__ Ms,
                                                   const int* __restrict__ rp,
                                                   const unsigned short* __restrict__ es,
                                                   unsigned short* __restrict__ H,
                                                   int n, int N) {
    constexpr int ECAP = 1280;
    __shared__ unsigned short esl[ECAP];
    __shared__ int rpl[65];
    __shared__ unsigned char perm[64];

    int tid = threadIdx.x;
    int s = blockIdx.x & 1;
    int t = blockIdx.x >> 1;
    int r0 = t * 64;

    const unsigned char* slab = Ms + (size_t)s * N * 64;

    // warm: same-XCD blocks (t = t0+4k) stream consecutive 16KB chunks
    {
        size_t off = ((size_t)(t >> 2) * 256 + tid) * 64;
        if (off + 64 <= (size_t)N * 64) {
            const uint4* wp = (const uint4*)(slab + off);
            uint4 a0 = wp[0], a1 = wp[1], a2 = wp[2], a3 = wp[3];
            asm volatile("" :: "v"(a0.x), "v"(a1.y), "v"(a2.z), "v"(a3.w));
        }
    }

    if (tid < 65) {
        int gi = r0 + tid;
        if (gi > n) gi = n;
        rpl[tid] = rp[gi];
    }
    __syncthreads();

    int ebase = rpl[0];
    int ecnt = rpl[64] - ebase;
    if (ecnt > ECAP) ecnt = ECAP;

    if (tid < 64) {
        int di = rpl[tid + 1] - rpl[tid];
        int rank = 0;
        for (int j = 0; j < 64; ++j) {
            int dj = rpl[j + 1] - rpl[j];
            rank += (dj > di) || (dj == di && j < tid);
        }
        perm[rank] = (unsigned char)tid;
    }
    for (int i = tid; i < ecnt; i += 256) esl[i] = es[ebase + i];
    __syncthreads();

    int gid = tid >> 2, ln = tid & 3;
    int nl = perm[gid];
    int beg = rpl[nl], end = rpl[nl + 1];
    int pbeg = beg - ebase, pend = end - ebase;
    int pm = pend < ecnt ? pend : ecnt;
    const unsigned char* base = slab + ln * 16;

    float a[16] = {};
    int p = pbeg;
    for (; p + 8 <= pm; p += 8) {
        int s0 = esl[p],     s1 = esl[p + 1], s2 = esl[p + 2], s3 = esl[p + 3];
        int s4 = esl[p + 4], s5 = esl[p + 5], s6 = esl[p + 6], s7 = esl[p + 7];
        uint4 v0 = *(const uint4*)(base + (size_t)s0 * 64);
        uint4 v1 = *(const uint4*)(base + (size_t)s1 * 64);
        uint4 v2 = *(const uint4*)(base + (size_t)s2 * 64);
        uint4 v3 = *(const uint4*)(base + (size_t)s3 * 64);
        uint4 v4 = *(const uint4*)(base + (size_t)s4 * 64);
        uint4 v5 = *(const uint4*)(base + (size_t)s5 * 64);
        uint4 v6 = *(const uint4*)(base + (size_t)s6 * 64);
        uint4 v7 = *(const uint4*)(base + (size_t)s7 * 64);
        acc16f(a, v0); acc16f(a, v1); acc16f(a, v2); acc16f(a, v3);
        acc16f(a, v4); acc16f(a, v5); acc16f(a, v6); acc16f(a, v7);
    }
    for (; p + 4 <= pm; p += 4) {
        int s0 = esl[p], s1 = esl[p + 1], s2 = esl[p + 2], s3 = esl[p + 3];
        uint4 v0 = *(const uint4*)(base + (size_t)s0 * 64);
        uint4 v1 = *(const uint4*)(base + (size_t)s1 * 64);
        uint4 v2 = *(const uint4*)(base + (size_t)s2 * 64);
        uint4 v3 = *(const uint4*)(base + (size_t)s3 * 64);
        acc16f(a, v0); acc16f(a, v1); acc16f(a, v2); acc16f(a, v3);
    }
    for (; p < pm; ++p) {
        uint4 v = *(const uint4*)(base + (size_t)esl[p] * 64);
        acc16f(a, v);
    }
    for (; p < pend; ++p) {   // overflow fallback (ecnt == total in practice)
        uint4 v = *(const uint4*)(base + (size_t)es[ebase + p] * 64);
        acc16f(a, v);
    }

    int node = r0 + nl;
    if (node < n) {
        unsigned long long* dst =
            (unsigned long long*)(H + (size_t)node * 128 + s * 64 + ln * 16);
#pragma unroll
        for (int k = 0; k < 4; ++k) {
            unsigned lo = (unsigned)f2bf(a[4 * k + 0]) | ((unsigned)f2bf(a[4 * k + 1]) << 16);
            unsigned hi = (unsigned)f2bf(a[4 * k + 2]) | ((unsigned)f2bf(a[4 * k + 3]) << 16);
            unsigned long long o = (unsigned long long)lo | ((unsigned long long)hi << 32);
            __builtin_nontemporal_store(o, dst + k);
        }
    }
}

// ---------------- gemm_pass: M_next = q8(relu?(H W + deg b)) [OUTCHAIN] -----
// Streams H bf16 row-major; W frags L2-hot; epilogue adds deg[row]*b[col];
// !OUTCHAIN writes fp8 slabbed M_next; OUTCHAIN: T=relu(HW+deg b) -> Hl
// round-trip -> 64x64 Wout MFMA -> fp32 out.

template <bool RELU, bool OUTCHAIN>
__global__ __launch_bounds__(256) void gemm_pass(const unsigned short* __restrict__ H,
                                                 const uint4* __restrict__ Whi,
                                                 const float* __restrict__ bvec,
                                                 const int* __restrict__ rp,
                                                 const uint4* __restrict__ Wof,
                                                 const float* __restrict__ bout,
                                                 void* __restrict__ Yv, int n, int N) {
    constexpr int SR = 136;
    __shared__ unsigned short Hl[64 * SR];
    __shared__ int rpl[65];

    int tid = threadIdx.x;
    int r0 = blockIdx.x * 64;

    if (tid < 65) {
        int gi = r0 + tid;
        if (gi > n) gi = n;
        rpl[tid] = rp[gi];
    }
    __syncthreads();

    int wave = tid >> 6, lane = tid & 63;
    int lm = lane & 15, lq = lane >> 4;

    f32x4 acc[4][2];
#pragma unroll
    for (int rt = 0; rt < 4; ++rt)
#pragma unroll
        for (int t = 0; t < 2; ++t)
            acc[rt][t] = (f32x4){0.f, 0.f, 0.f, 0.f};

#pragma unroll
    for (int c = 0; c < 4; ++c) {
        bf16x8 afr[4];
#pragma unroll
        for (int rt = 0; rt < 4; ++rt)
            afr[rt] = *(const bf16x8*)(H + (size_t)(r0 + rt * 16 + lm) * 128 + c * 32 + lq * 8);
#pragma unroll
        for (int t = 0; t < 2; ++t) {
            uint4 uh = Whi[((wave * 2 + t) * 4 + c) * 64 + lane];
            bf16x8 wh = *(const bf16x8*)&uh;
#pragma unroll
            for (int rt = 0; rt < 4; ++rt)
                acc[rt][t] = __builtin_amdgcn_mfma_f32_16x16x32_bf16(afr[rt], wh, acc[rt][t], 0, 0, 0);
        }
    }

    if (!OUTCHAIN) {
#pragma unroll
        for (int t = 0; t < 2; ++t) {
            int col = (wave * 2 + t) * 16 + lm;
            int sl = col >> 6, c64 = col & 63;
            float bv = bvec[col];
#pragma unroll
            for (int rt = 0; rt < 4; ++rt) {
#pragma unroll
                for (int r = 0; r < 4; ++r) {
                    int rowl = rt * 16 + lq * 4 + r;
                    int row = r0 + rowl;
                    if (row < n) {
                        float deg = (float)(rpl[rowl + 1] - rpl[rowl]);
                        float v = acc[rt][t][r] + deg * bv;
                        if (RELU) v = fmaxf(v, 0.f);
                        ((unsigned char*)Yv)[(size_t)sl * N * 64 + (size_t)row * 64 + c64] = f2fp8(v);
                    }
                }
            }
        }
    } else {
#pragma unroll
        for (int t = 0; t < 2; ++t) {
            int col = (wave * 2 + t) * 16 + lm;
            float bv = bvec[col];
#pragma unroll
            for (int rt = 0; rt < 4; ++rt) {
#pragma unroll
                for (int r = 0; r < 4; ++r) {
                    int rowl = rt * 16 + lq * 4 + r;
                    float deg = (float)(rpl[rowl + 1] - rpl[rowl]);
                    float v = acc[rt][t][r] + deg * bv;
                    v = fmaxf(v, 0.f);           // ReLU always on the chain
                    Hl[rowl * SR + col] = f2bf(v);
                }
            }
        }
        __syncthreads();

        // Phase C: 64x64 Wout tile; wave = one 16-col tile
        f32x4 acc2[4];
#pragma unroll
        for (int rt = 0; rt < 4; ++rt) acc2[rt] = (f32x4){0.f, 0.f, 0.f, 0.f};

#pragma unroll
        for (int c = 0; c < 4; ++c) {
            bf16x8 afr[4];
#pragma unroll
            for (int rt = 0; rt < 4; ++rt)
                afr[rt] = *(const bf16x8*)(&Hl[(rt * 16 + lm) * SR + c * 32 + lq * 8]);
            uint4 uw = Wof[(wave * 4 + c) * 64 + lane];
            bf16x8 wf = *(const bf16x8*)&uw;
#pragma unroll
            for (int rt = 0; rt < 4; ++rt)
                acc2[rt] = __builtin_amdgcn_mfma_f32_16x16x32_bf16(afr[rt], wf, acc2[rt], 0, 0, 0);
        }

        int col = wave * 16 + lm;
        float bo = bout[col];
#pragma unroll
        for (int rt = 0; rt < 4; ++rt) {
#pragma unroll
            for (int r = 0; r < 4; ++r) {
                int row = r0 + rt * 16 + lq * 4 + r;
                if (row < n)
                    ((float*)Yv)[(size_t)row * 64 + col] = acc2[rt][r] + bo;
            }
        }
    }
}

// ---------------- Launch ----------------

extern "C" void kernel_launch(void* const* d_in, const int* in_sizes, int n_in,
                              void* d_out, int out_size, void* d_ws, size_t ws_size,
                              hipStream_t stream) {
    const float* x    = (const float*)d_in[0];
    const int*   ei   = (const int*)d_in[1];
    const float* W1   = (const float*)d_in[2];
    const float* b1   = (const float*)d_in[3];
    const float* W2   = (const float*)d_in[4];
    const float* b2   = (const float*)d_in[5];
    const float* Wout = (const float*)d_in[6];
    const float* bout = (const float*)d_in[7];
    float*       out  = (float*)d_out;

    const int N = in_sizes[0] / 128;
    const int E = in_sizes[1] / 2;
    const int* src = ei;
    const int* dst = ei + E;

    const int tiles64 = ceil_div(N, 64);
    const int nChunks = ceil_div(N + 1, 256);

    char* ws = (char*)d_ws;
    auto take = [&](size_t bytes) {
        char* p = ws;
        ws += (bytes + 255) & ~(size_t)255;
        return p;
    };
    unsigned char* mS0 = (unsigned char*)take((size_t)N * 128);        // fp8 slabbed
    unsigned char* mS1 = (unsigned char*)take((size_t)N * 128);        // fp8 slabbed
    unsigned short* Hb = (unsigned short*)take((size_t)tiles64 * 64 * 128 * 2);  // padded rows
    unsigned short* W1hi = (unsigned short*)take(128 * 128 * 2);
    unsigned short* W2hi = (unsigned short*)take(128 * 128 * 2);
    unsigned short* Wohi = (unsigned short*)take(128 * 64 * 2);
    int* rp      = (int*)take((size_t)(N + 1) * sizeof(int));
    int* cursor  = (int*)take((size_t)N * sizeof(int));
    unsigned short* es = (unsigned short*)take((size_t)E * sizeof(unsigned short));
    unsigned* stat = (unsigned*)take(4096);

    prep_kernel<<<256, 256, 0, stream>>>(x, W1, W2, Wout, (unsigned*)mS0,
                                         W1hi, W2hi, Wohi, cursor, stat, N, nChunks);
    hist_kernel<<<ceil_div(E, 256), 256, 0, stream>>>(dst, cursor, E);
    scan_fuse_kernel<<<nChunks, 256, 0, stream>>>(cursor, rp, cursor, stat, N);
    fill_kernel<<<ceil_div(E, 256), 256, 0, stream>>>(src, dst, cursor, es, E);

    // L1: M1 = (S x) W1 + d b1
    gather_pass<<<tiles64 * 2, 256, 0, stream>>>(mS0, rp, es, Hb, N, N);
    gemm_pass<false, false><<<tiles64, 256, 0, stream>>>(Hb, (const uint4*)W1hi, b1, rp,
                                                         nullptr, nullptr, mS1, N, N);
    // L2: M2 = relu((S x1) W1 + d b1)
    gather_pass<<<tiles64 * 2, 256, 0, stream>>>(mS1, rp, es, Hb, N, N);
    gemm_pass<true, false><<<tiles64, 256, 0, stream>>>(Hb, (const uint4*)W1hi, b1, rp,
                                                        nullptr, nullptr, mS0, N, N);
    // L3: M3 = (S h) W2 + d b2
    gather_pass<<<tiles64 * 2, 256, 0, stream>>>(mS0, rp, es, Hb, N, N);
    gemm_pass<false, false><<<tiles64, 256, 0, stream>>>(Hb, (const uint4*)W2hi, b2, rp,
                                                         nullptr, nullptr, mS1, N, N);
    // L4: out = relu((S h1) W2 + d b2) @ Wout + bout
    gather_pass<<<tiles64 * 2, 256, 0, stream>>>(mS1, rp, es, Hb, N, N);
    gemm_pass<true, true><<<tiles64, 256, 0, stream>>>(Hb, (const uint4*)W2hi, b2, rp,
                                                       (const uint4*)Wohi, bout, out, N, N);
}